// Round 11
// baseline (63.531 us; speedup 1.0000x reference)
//
#include <hip/hip_runtime.h>

// FEM stiffness matrix assembly (negated): out = -M, dense N x N (N = 9216).
//
// R11: single fused dispatch, WG=512 variant (one f32x4 store per thread,
// 8 KB/WG, 41,472 WGs). Isolates per-WG bytes from stores-per-thread:
//  - R8/R10: 1 store/thread, 256-thread WGs (4 KB/WG, 82,944 WGs) -> 5.9 TB/s
//  - R9: 4 stores/thread, 256-thread WGs (16 KB/WG, 20,736 WGs) -> 5.1 TB/s
//  - R6: NT stores -> 4x partial-line RMW fetch blowup, ~1 TB/s. Plain stores.
//
// Grid: (9, 4608) x 512 threads. Each y-block covers a PAIR of rows
// (4608 f32x4 vectors, contiguous); no runtime div/mod, no tails at N=9216.
// Off-band threads (~99.7%) store zeros; band threads gather their <=6
// incident triangles from the structured mesh and compute final values.

typedef float f32x4 __attribute__((ext_vector_type(4)));

__global__ void __launch_bounds__(512) fused_write_kernel(
        const float* __restrict__ pts,
        float* __restrict__ out,
        int n,        // mesh side (96)
        int N) {      // n*n (9216)
    int vpr = N >> 2;                       // f32x4 vectors per row (2304)
    int lv = blockIdx.x * 512 + threadIdx.x;  // vector index within row-pair
    int r = blockIdx.y * 2;
    if (lv >= vpr) { r += 1; lv -= vpr; }   // second row of the pair
    if (lv >= vpr || r >= N) return;        // generality guard (no-op here)
    int c0 = lv << 2;                       // first column of my vector

    f32x4 val = (f32x4){0.f, 0.f, 0.f, 0.f};

    // Band test: does [c0, c0+3] hit {r-n-1, r-n, r-1, r, r+1, r+n, r+n+1}?
    int d = c0 - r;
    bool slow = (d >= -(n + 5) && d <= -(n + 0)) ||   // cluster {r-n-1, r-n}
                (d >= -4 && d <= 1) ||                // cluster {r-1, r, r+1}
                (d >= (n - 3) && d <= (n + 1));       // cluster {r+n, r+n+1}

    if (slow) {
        int ri = r / n, rj = r % n;
        float a0 = 0.f, a1 = 0.f, a2 = 0.f, a3 = 0.f;

        // 6 candidate incident triangles of node r:
        //  k=0: T1(ri,  rj  )  nodes v00, v10, v11
        //  k=1: T1(ri-1,rj  )
        //  k=2: T1(ri-1,rj-1)
        //  k=3: T2(ri,  rj  )  nodes v00, v11, v01
        //  k=4: T2(ri-1,rj-1)
        //  k=5: T2(ri,  rj-1)
        #pragma unroll
        for (int k = 0; k < 6; ++k) {
            int ci, cj; bool isT1;
            switch (k) {
                case 0: ci = ri;     cj = rj;     isT1 = true;  break;
                case 1: ci = ri - 1; cj = rj;     isT1 = true;  break;
                case 2: ci = ri - 1; cj = rj - 1; isT1 = true;  break;
                case 3: ci = ri;     cj = rj;     isT1 = false; break;
                case 4: ci = ri - 1; cj = rj - 1; isT1 = false; break;
                default: ci = ri;    cj = rj - 1; isT1 = false; break;
            }
            if (ci < 0 || cj < 0 || ci > n - 2 || cj > n - 2) continue;

            int v00 = ci * n + cj;
            int na = v00;
            int nb = isT1 ? (v00 + n) : (v00 + n + 1);
            int nc = isT1 ? (v00 + n + 1) : (v00 + 1);

            float x0 = pts[2 * na], y0 = pts[2 * na + 1];
            float x1 = pts[2 * nb], y1 = pts[2 * nb + 1];
            float x2 = pts[2 * nc], y2 = pts[2 * nc + 1];

            float det = (x1 - x0) * (y2 - y0) - (x2 - x0) * (y1 - y0);
            float area = 0.5f * fabsf(det);
            float inv = 1.0f / det;

            float g0x = (y1 - y2) * inv, g0y = (x2 - x1) * inv;
            float g1x = (y2 - y0) * inv, g1y = (x0 - x2) * inv;
            float g2x = (y0 - y1) * inv, g2y = (x1 - x0) * inv;

            // gradient of node r inside this triangle
            float grx, gry;
            if (na == r)      { grx = g0x; gry = g0y; }
            else if (nb == r) { grx = g1x; gry = g1y; }
            else              { grx = g2x; gry = g2y; }

            float w0 = (grx * g0x + gry * g0y) * area;
            float w1 = (grx * g1x + gry * g1y) * area;
            float w2 = (grx * g2x + gry * g2y) * area;

            int o;
            o = na - c0;
            if (o == 0) a0 += w0; else if (o == 1) a1 += w0;
            else if (o == 2) a2 += w0; else if (o == 3) a3 += w0;
            o = nb - c0;
            if (o == 0) a0 += w1; else if (o == 1) a1 += w1;
            else if (o == 2) a2 += w1; else if (o == 3) a3 += w1;
            o = nc - c0;
            if (o == 0) a0 += w2; else if (o == 1) a1 += w2;
            else if (o == 2) a2 += w2; else if (o == 3) a3 += w2;
        }
        val = (f32x4){-a0, -a1, -a2, -a3};
    }

    *((f32x4*)(out + (size_t)r * N + c0)) = val;
}

extern "C" void kernel_launch(void* const* d_in, const int* in_sizes, int n_in,
                              void* d_out, int out_size, void* d_ws, size_t ws_size,
                              hipStream_t stream) {
    const float* pts = (const float*)d_in[0];   // (N, 2) float32
    int N = in_sizes[0] / 2;                    // 9216 nodes
    int n = 1;
    while ((n + 1) * (n + 1) <= N) ++n;         // integer sqrt (96)

    float* out = (float*)d_out;

    int vpr = N >> 2;                            // 2304 vectors per row
    int xblocks = (2 * vpr + 511) / 512;         // 9 blocks per row-pair
    dim3 grid(xblocks, (N + 1) / 2);             // (9, 4608) = 41,472 WGs
    fused_write_kernel<<<grid, 512, 0, stream>>>(pts, out, n, N);
}

// Round 12
// 61.709 us; speedup vs baseline: 1.0295x; 1.0295x over previous
//
#include <hip/hip_runtime.h>

// FEM stiffness matrix assembly (negated): out = -M, dense N x N (N = 9216).
//
// FINAL (= R10, best measured: 61.7 us). Single fused dispatch in the
// empirically optimal fill shape: 82,944 WGs x 256 threads, one f32x4 plain
// store per thread. Off-band threads (~99.7%) store zeros; band threads
// gather their <=6 incident triangles (structured-mesh adjacency) and
// compute final stiffness values directly. absmax 6e-8 vs reference.
//
// Shape evidence (340 MB fill rate, total-time A/B):
//  - nontemporal stores: 4x partial-line RMW fetch blowup -> ~1 TB/s   (R6)
//  - looped 54 vec/thread, 1536 WGs:                      ~5.1 TB/s    (R7)
//  - 4 straight-line stores/thread, 20,736 WGs:           ~5.1 TB/s    (R9)
//  - 1 store/thread, WG=512, 41,472 WGs:                  ~5.7 TB/s    (R11)
//  - 1 store/thread, WG=256, 82,944 WGs:                  ~5.9 TB/s    (R8/R10)
// Structural floor: 340 MB / 5.9 TB/s + launch ~= 61 us. The 6.97 TB/s seen
// on the harness's 1.36 GB poison fill is a large-transfer asymptote (fixed
// ramp/drain amortized), not reachable at this output size.

typedef float f32x4 __attribute__((ext_vector_type(4)));

__global__ void __launch_bounds__(256) fused_write_kernel(
        const float* __restrict__ pts,
        float* __restrict__ out,
        int n,        // mesh side (96)
        int N) {      // n*n (9216)
    int r = blockIdx.y;                                // output row (uniform)
    int c0 = (blockIdx.x * 256 + threadIdx.x) << 2;    // first col of my vec
    if (c0 >= N) return;

    f32x4 val = (f32x4){0.f, 0.f, 0.f, 0.f};

    // Band test: does [c0, c0+3] hit {r-n-1, r-n, r-1, r, r+1, r+n, r+n+1}?
    int d = c0 - r;
    bool slow = (d >= -(n + 5) && d <= -(n + 0)) ||   // cluster {r-n-1, r-n}
                (d >= -4 && d <= 1) ||                // cluster {r-1, r, r+1}
                (d >= (n - 3) && d <= (n + 1));       // cluster {r+n, r+n+1}

    if (slow) {
        int ri = r / n, rj = r % n;
        float a0 = 0.f, a1 = 0.f, a2 = 0.f, a3 = 0.f;

        // 6 candidate incident triangles of node r:
        //  k=0: T1(ri,  rj  )  nodes v00, v10, v11
        //  k=1: T1(ri-1,rj  )
        //  k=2: T1(ri-1,rj-1)
        //  k=3: T2(ri,  rj  )  nodes v00, v11, v01
        //  k=4: T2(ri-1,rj-1)
        //  k=5: T2(ri,  rj-1)
        #pragma unroll
        for (int k = 0; k < 6; ++k) {
            int ci, cj; bool isT1;
            switch (k) {
                case 0: ci = ri;     cj = rj;     isT1 = true;  break;
                case 1: ci = ri - 1; cj = rj;     isT1 = true;  break;
                case 2: ci = ri - 1; cj = rj - 1; isT1 = true;  break;
                case 3: ci = ri;     cj = rj;     isT1 = false; break;
                case 4: ci = ri - 1; cj = rj - 1; isT1 = false; break;
                default: ci = ri;    cj = rj - 1; isT1 = false; break;
            }
            if (ci < 0 || cj < 0 || ci > n - 2 || cj > n - 2) continue;

            int v00 = ci * n + cj;
            int na = v00;
            int nb = isT1 ? (v00 + n) : (v00 + n + 1);
            int nc = isT1 ? (v00 + n + 1) : (v00 + 1);

            float x0 = pts[2 * na], y0 = pts[2 * na + 1];
            float x1 = pts[2 * nb], y1 = pts[2 * nb + 1];
            float x2 = pts[2 * nc], y2 = pts[2 * nc + 1];

            float det = (x1 - x0) * (y2 - y0) - (x2 - x0) * (y1 - y0);
            float area = 0.5f * fabsf(det);
            float inv = 1.0f / det;

            float g0x = (y1 - y2) * inv, g0y = (x2 - x1) * inv;
            float g1x = (y2 - y0) * inv, g1y = (x0 - x2) * inv;
            float g2x = (y0 - y1) * inv, g2y = (x1 - x0) * inv;

            // gradient of node r inside this triangle
            float grx, gry;
            if (na == r)      { grx = g0x; gry = g0y; }
            else if (nb == r) { grx = g1x; gry = g1y; }
            else              { grx = g2x; gry = g2y; }

            // accumulate (grad_r . grad_m) * area into matching window slots
            float w0 = (grx * g0x + gry * g0y) * area;
            float w1 = (grx * g1x + gry * g1y) * area;
            float w2 = (grx * g2x + gry * g2y) * area;

            int o;
            o = na - c0;
            if (o == 0) a0 += w0; else if (o == 1) a1 += w0;
            else if (o == 2) a2 += w0; else if (o == 3) a3 += w0;
            o = nb - c0;
            if (o == 0) a0 += w1; else if (o == 1) a1 += w1;
            else if (o == 2) a2 += w1; else if (o == 3) a3 += w1;
            o = nc - c0;
            if (o == 0) a0 += w2; else if (o == 1) a1 += w2;
            else if (o == 2) a2 += w2; else if (o == 3) a3 += w2;
        }
        val = (f32x4){-a0, -a1, -a2, -a3};
    }

    *((f32x4*)(out + (size_t)r * N + c0)) = val;
}

extern "C" void kernel_launch(void* const* d_in, const int* in_sizes, int n_in,
                              void* d_out, int out_size, void* d_ws, size_t ws_size,
                              hipStream_t stream) {
    const float* pts = (const float*)d_in[0];   // (N, 2) float32
    int N = in_sizes[0] / 2;                    // 9216 nodes
    int n = 1;
    while ((n + 1) * (n + 1) <= N) ++n;         // integer sqrt (96)

    float* out = (float*)d_out;

    int vpr = N >> 2;                            // vectors per row (2304)
    dim3 grid((vpr + 255) / 256, N);             // (9, 9216) = 82,944 WGs
    fused_write_kernel<<<grid, 256, 0, stream>>>(pts, out, n, N);
}